// Round 13
// baseline (175.602 us; speedup 1.0000x reference)
//
#include <hip/hip_runtime.h>
#include <stdint.h>

typedef __attribute__((ext_vector_type(8))) short short8;
typedef __attribute__((ext_vector_type(16))) float f32x16;

#define NB 32

__device__ __forceinline__ uint16_t f2bf(float f) {
    uint32_t u = __float_as_uint(f);
    u += 0x7fffu + ((u >> 16) & 1u);   // RNE
    return (uint16_t)(u >> 16);
}

// async global(16B) -> LDS, linear dest (wave-uniform base + lane*16)
__device__ __forceinline__ void gload16(const void* g, void* l) {
    __builtin_amdgcn_global_load_lds(
        (const __attribute__((address_space(1))) uint32_t*)g,
        (__attribute__((address_space(3))) uint32_t*)l, 16, 0, 0);
}

// ------- weight prep item: w[b][oc][ci][3][3] f32 -> wp[b][kk][oc][ci] bf16
template<int COUT, int CIN>
__device__ __forceinline__ void prep_w_item(int idx, const float* __restrict__ w,
                                            uint16_t* __restrict__ wp)
{
    const int ci = idx % CIN;
    const int t  = idx / CIN;
    const int oc = t % COUT;
    const int b  = t / COUT;
    const float* s = w + (size_t)idx * 9;
    #pragma unroll
    for (int k = 0; k < 9; k++)
        wp[((size_t)(b * 9 + k) * COUT + oc) * CIN + ci] = f2bf(s[k]);
}

// ------- standalone w3 prep (aliased-ws mode: must run AFTER conv2) --------
__global__ __launch_bounds__(256) void prep_w3_k(
    const float* __restrict__ w, uint16_t* __restrict__ wp)
{
    const int idx = blockIdx.x * 256 + threadIdx.x;
    if (idx < NB * 256 * 128) prep_w_item<256, 128>(idx, w, wp);
}

// ------- fused prep: zero-page + x->NHWC16 bf16 + w1 + w2 (+ w3) -----------
template<bool DO_W3>
__global__ __launch_bounds__(256) void prep_all(
    const float* __restrict__ x,  const float* __restrict__ w1,
    const float* __restrict__ w2, const float* __restrict__ w3,
    uint16_t* __restrict__ xp,  uint16_t* __restrict__ wp1,
    uint16_t* __restrict__ wp2, uint16_t* __restrict__ wp3,
    float* __restrict__ zp)
{
    int idx = blockIdx.x * 256 + threadIdx.x;
    if (idx < 4096) {                          // zero page (64 KB)
        ((float4*)zp)[idx] = make_float4(0.f, 0.f, 0.f, 0.f);
        return;
    }
    idx -= 4096;
    if (idx < 131072) {                        // x: NCHW f32 -> NHWC(ci=16) bf16
        const int xc = idx & 63, y = (idx >> 6) & 63, b = idx >> 12;
        const float* s = x + (size_t)b * 3 * 4096 + y * 64 + xc;
        const uint16_t v0 = f2bf(s[0]), v1 = f2bf(s[4096]), v2 = f2bf(s[8192]);
        short8 lo = {(short)v0, (short)v1, (short)v2, 0, 0, 0, 0, 0};
        short8 hi = {0, 0, 0, 0, 0, 0, 0, 0};
        uint16_t* d = xp + (size_t)idx * 16;
        *(short8*)d = lo;
        *(short8*)(d + 8) = hi;
        return;
    }
    idx -= 131072;
    if (idx < 18432) {                         // w1 -> wp1[b][kk][oc][ci=16]
        const int oc = idx & 63, k = (idx >> 6) % 9, b = idx / 576;
        const uint16_t v0 = f2bf(w1[((size_t)(b * 64 + oc) * 3 + 0) * 9 + k]);
        const uint16_t v1 = f2bf(w1[((size_t)(b * 64 + oc) * 3 + 1) * 9 + k]);
        const uint16_t v2 = f2bf(w1[((size_t)(b * 64 + oc) * 3 + 2) * 9 + k]);
        short8 lo = {(short)v0, (short)v1, (short)v2, 0, 0, 0, 0, 0};
        short8 hi = {0, 0, 0, 0, 0, 0, 0, 0};
        uint16_t* d = wp1 + ((size_t)(b * 9 + k) * 64 + oc) * 16;
        *(short8*)d = lo;
        *(short8*)(d + 8) = hi;
        return;
    }
    idx -= 18432;
    if (idx < 262144) {                        // w2
        prep_w_item<128, 64>(idx, w2, wp2);
        return;
    }
    if (!DO_W3) return;
    idx -= 262144;
    if (idx < 1048576) prep_w_item<256, 128>(idx, w3, wp3);
}

// ---------------- MFMA implicit-GEMM conv, 3x3 SAME, ReLU ------------------
// R13: FAT-ACCUMULATOR waves. Block = 4 rows x 64 px x (NF*64) oc,
// 256 threads / 4 waves as 2M x 2N; wave tile = 128 px x (NF*32) oc ->
// acc = 4 x NF f32x16 (NF=4: 256 regs, 1 wave/SIMD owning the 512-reg file).
// Per kx: 4 A-reads + NF B-reads -> 4*NF MFMA (NF=4: ratio 2.0 MFMA/read) ->
// per-CU-phase LDS ~1416 cyc < MFMA 1536 cyc: MFMA-bound structure.
// Phases = 3 ky x CIN/16 ci-chunks; per phase stage 4 input rows (this ky)
// + 3-kx weight panel; conflict-free linear granule layout (R10-verified):
// input [rq=t*2+q][px 0..65], weights [kx*2+q][oc]. Double-buffered, R7-
// proven sync (stage-next; compute; vmcnt(0)+barrier). kx reg ping-pong +
// sched_barrier(0) for LDS/MFMA overlap within the wave.
// Grid 1D, XCD-pinned: batch b -> XCD b%8 (P=16 stripe-blocks per batch).
template<int CIN, int COUT, int NF, bool POOL>
__global__ __launch_bounds__(256, 1) void conv_mfma(
    const uint16_t* __restrict__ in, const uint16_t* __restrict__ wp,
    const float* __restrict__ bias, uint16_t* __restrict__ out,
    float* __restrict__ partial, const float* __restrict__ zp)
{
    constexpr int IN_B  = 9216;              // 576 granule slots (528 used)
    constexpr int W_B   = NF * 6144;         // NF*384 granules
    constexpr int BUF_B = IN_B + W_B;        // NF4: 33792 B
    constexpr int TOT   = 9 + NF * 6;        // staging chunks (64 granules)
    constexpr int CPW   = (TOT + 3) / 4;     // chunks per wave
    constexpr int NP    = 3 * (CIN / 16);    // phases = ky x ci-chunk
    constexpr int NW64  = NF * 64;           // block N (= COUT here)
    extern __shared__ __align__(16) char sm[];
    // layout: buf0 | buf1 | 2048 B (dummy sink + POOL red[2][NW64])

    // ---- XCD-pinned decode: 16 stripe-blocks per batch
    const int L   = blockIdx.x;
    const int xcd = L & 7;
    const int jj  = L >> 3;
    const int b   = (jj >> 4) * 8 + xcd;
    const int stripe = jj & 15;
    const int y0 = stripe * 4;

    const int tid = threadIdx.x;
    const int w = tid >> 6, l = tid & 63, q = l >> 5, ln = l & 31;
    const int wvM = w >> 1, wvN = w & 1;

    // ---- per-chunk staging invariants
    const uint16_t* cptr[CPW];   // input: base sans row; weight: base (ky=0,c=0)
    int ldsoff[CPW];             // -1 = dummy
    int gy0a[CPW];               // input: y0-1+t
    bool isin[CPW], vpx[CPW];
    #pragma unroll
    for (int j = 0; j < CPW; j++) {
        const int chunk = w * CPW + j;
        isin[j] = false; vpx[j] = false; gy0a[j] = 0;
        if (chunk >= TOT) {                    // dummy
            cptr[j] = (const uint16_t*)zp;
            ldsoff[j] = -1;
        } else if (chunk < 9) {                // input granule gi=[rq][px]
            const int gi = chunk * 64 + l;
            const int rq = gi / 66, px = gi - rq * 66;
            const int t = rq >> 1, qq = rq & 1;
            const int gx = px - 1;
            isin[j] = true;
            vpx[j] = (gi < 528) && ((unsigned)gx < 64u);
            gy0a[j] = y0 - 1 + t;
            cptr[j] = in + ((size_t)(b * 64) * 64 + gx) * CIN + qq * 8;
            ldsoff[j] = chunk * 1024;
        } else {                               // weight granule [kx*2+q][oc]
            const int wgi = (chunk - 9) * 64 + l;
            const int kx = wgi / (NF * 128);
            const int qq = (wgi / NW64) & 1;
            const int oc = wgi % NW64;
            cptr[j] = wp + ((size_t)(b * 9 + kx) * COUT + oc) * CIN + qq * 8;
            ldsoff[j] = IN_B + (chunk - 9) * 1024;
        }
    }

    // ---- LDS read offsets (bytes)
    int aoffA[4];                 // dh = dr*2+h ; +kx*16 at use
    #pragma unroll
    for (int dh = 0; dh < 4; dh++) {
        const int dr = dh >> 1, h = dh & 1;
        const int t = wvM * 2 + dr;
        aoffA[dh] = ((t * 2 + q) * 66 + h * 32 + ln) * 16;
    }
    int bbase[NF];                // +kx*(NF*2048) at use
    #pragma unroll
    for (int n = 0; n < NF; n++)
        bbase[n] = IN_B + (q * NW64 + wvN * (NF * 32) + n * 32 + ln) * 16;

    f32x16 acc[4][NF];
    {
        #pragma unroll
        for (int n = 0; n < NF; n++) {
            const float bv = bias[b * COUT + wvN * (NF * 32) + n * 32 + ln];
            #pragma unroll
            for (int dh = 0; dh < 4; dh++)
                #pragma unroll
                for (int r = 0; r < 16; r++) acc[dh][n][r] = bv;
        }
    }

    auto stage = [&](int bufsel, int p) {
        const int ky = p % 3, c = p / 3;
        const size_t woff = (size_t)(3 * ky) * COUT * CIN + c * 16;
        char* base = sm + bufsel * BUF_B;
        #pragma unroll
        for (int j = 0; j < CPW; j++) {
            const uint16_t* src;
            char* dst;
            if (ldsoff[j] < 0) {
                src = (const uint16_t*)zp; dst = sm + 2 * BUF_B;
            } else if (isin[j]) {
                const int gy = gy0a[j] + ky;
                const bool v = vpx[j] && ((unsigned)gy < 64u);
                src = v ? cptr[j] + (size_t)gy * (64 * CIN) + c * 16
                        : (const uint16_t*)zp;
                dst = base + ldsoff[j];
            } else {
                src = cptr[j] + woff; dst = base + ldsoff[j];
            }
            gload16(src, dst);
        }
    };

    stage(0, 0);
    asm volatile("s_waitcnt vmcnt(0)" ::: "memory");
    __syncthreads();

    for (int p = 0; p < NP; p++) {
        const char* cb = sm + (p & 1) * BUF_B;
        if (p + 1 < NP) stage((p + 1) & 1, p + 1);

        short8 cA[4], cB[NF], nA[4], nB[NF];
        #pragma unroll
        for (int dh = 0; dh < 4; dh++)
            cA[dh] = *(const short8*)(cb + aoffA[dh]);
        #pragma unroll
        for (int n = 0; n < NF; n++)
            cB[n] = *(const short8*)(cb + bbase[n]);
        __builtin_amdgcn_s_setprio(1);
        #pragma unroll
        for (int kx = 0; kx < 3; kx++) {
            if (kx < 2) {
                #pragma unroll
                for (int dh = 0; dh < 4; dh++)
                    nA[dh] = *(const short8*)(cb + aoffA[dh] + (kx + 1) * 16);
                #pragma unroll
                for (int n = 0; n < NF; n++)
                    nB[n] = *(const short8*)(cb + bbase[n] + (kx + 1) * (NF * 2048));
            }
            __builtin_amdgcn_sched_barrier(0);   // loads stay above MFMAs
            #pragma unroll
            for (int dh = 0; dh < 4; dh++)
                #pragma unroll
                for (int n = 0; n < NF; n++)
                    acc[dh][n] = __builtin_amdgcn_mfma_f32_32x32x16_bf16(
                        cA[dh], cB[n], acc[dh][n], 0, 0, 0);
            if (kx < 2) {
                #pragma unroll
                for (int dh = 0; dh < 4; dh++) cA[dh] = nA[dh];
                #pragma unroll
                for (int n = 0; n < NF; n++) cB[n] = nB[n];
            }
        }
        __builtin_amdgcn_s_setprio(0);
        asm volatile("s_waitcnt vmcnt(0)" ::: "memory");
        __syncthreads();
    }

    if (!POOL) {
        #pragma unroll
        for (int dh = 0; dh < 4; dh++) {
            const int dr = dh >> 1, h = dh & 1;
            const int row = y0 + wvM * 2 + dr;
            #pragma unroll
            for (int r = 0; r < 16; r++) {
                const int px = h * 32 + (r & 3) + 8 * (r >> 2) + 4 * q;
                uint16_t* d = out + (size_t)((b * 64 + row) * 64 + px) * COUT
                              + wvN * (NF * 32);
                #pragma unroll
                for (int n = 0; n < NF; n++)
                    d[n * 32 + ln] = f2bf(fmaxf(acc[dh][n][r], 0.f));
            }
        }
    } else {
        float* red = (float*)(sm + 2 * BUF_B);   // [2][NW64]
        #pragma unroll
        for (int n = 0; n < NF; n++) {
            float s = 0.f;
            #pragma unroll
            for (int dh = 0; dh < 4; dh++)
                #pragma unroll
                for (int r = 0; r < 16; r++) s += fmaxf(acc[dh][n][r], 0.f);
            s += __shfl_xor(s, 32);              // combine q px-halves
            if (q == 0) red[wvM * NW64 + wvN * (NF * 32) + n * 32 + ln] = s;
        }
        __syncthreads();
        if (tid < NW64) {
            float t = red[tid] + red[NW64 + tid];
            partial[(size_t)(b * COUT + tid) * 16 + stripe] = t;
        }
    }
}

// ------- pooled mean + outer product with fc weight + bias4 ----------------
__global__ void fc_k(const float* __restrict__ partial,
                     const float* __restrict__ fcw,
                     const float* __restrict__ b4, float* __restrict__ out)
{
    const int b = blockIdx.x, c = threadIdx.x;   // 32 x 256
    const float* p = partial + (size_t)(b * 256 + c) * 16;
    float s = 0.f;
    #pragma unroll
    for (int i = 0; i < 16; i++) s += p[i];
    const float pooled = s * (1.f / 4096.f);
    #pragma unroll
    for (int o = 0; o < 10; o++)
        out[(b * 256 + c) * 10 + o] = fmaf(pooled, fcw[b * 10 + o], b4[b * 10 + o]);
}

extern "C" void kernel_launch(void* const* d_in, const int* in_sizes, int n_in,
                              void* d_out, int out_size, void* d_ws, size_t ws_size,
                              hipStream_t stream)
{
    const float* x   = (const float*)d_in[0];
    const float* w1  = (const float*)d_in[1];
    const float* w2  = (const float*)d_in[2];
    const float* w3  = (const float*)d_in[3];
    const float* fcw = (const float*)d_in[4];
    const float* b1  = (const float*)d_in[5];
    const float* b2  = (const float*)d_in[6];
    const float* b3  = (const float*)d_in[7];
    const float* b4  = (const float*)d_in[8];
    char* ws = (char*)d_ws;
    // Regions (see R6 notes): xp/wp1 alias dead-until-conv2 h2 space.
    uint16_t* xp  = (uint16_t*)(ws);
    uint16_t* wp1 = (uint16_t*)(ws + 4194304);
    uint16_t* h2  = (uint16_t*)(ws);
    uint16_t* h1  = (uint16_t*)(ws + 33554432);
    uint16_t* wp2 = (uint16_t*)(ws + 50331648);
    const bool big_ws = ws_size >= 74448896u;
    uint16_t* wp3     = (uint16_t*)(ws + (big_ws ? 55050240u : 33554432u));
    float*    partial = (float*)   (ws + (big_ws ? 73924608u : 52428800u));
    float*    zp      = (float*)d_out;   // first 64 KB zeroed by prep_all

    constexpr int DYN1 = 2 * (9216 + 1 * 6144) + 2048;   // 32768
    constexpr int DYN2 = 2 * (9216 + 2 * 6144) + 2048;   // 45056
    constexpr int DYN4 = 2 * (9216 + 4 * 6144) + 2048;   // 69632
    static bool attr_done = false;
    if (!attr_done) {   // host-side attribute set; not a stream op (capture-safe)
        hipFuncSetAttribute((const void*)&conv_mfma<16, 64, 1, false>,
                            hipFuncAttributeMaxDynamicSharedMemorySize, DYN1);
        hipFuncSetAttribute((const void*)&conv_mfma<64, 128, 2, false>,
                            hipFuncAttributeMaxDynamicSharedMemorySize, DYN2);
        hipFuncSetAttribute((const void*)&conv_mfma<128, 256, 4, true>,
                            hipFuncAttributeMaxDynamicSharedMemorySize, DYN4);
        attr_done = true;
    }

    if (big_ws) {
        prep_all<true><<<5720, 256, 0, stream>>>(x, w1, w2, w3, xp, wp1, wp2, wp3, zp);
    } else {
        prep_all<false><<<1624, 256, 0, stream>>>(x, w1, w2, w3, xp, wp1, wp2, wp3, zp);
    }
    conv_mfma<16, 64, 1, false><<<NB * 16, 256, DYN1, stream>>>(xp, wp1, b1, h1, nullptr, zp);
    conv_mfma<64, 128, 2, false><<<NB * 16, 256, DYN2, stream>>>(h1, wp2, b2, h2, nullptr, zp);
    if (!big_ws)
        prep_w3_k<<<4096, 256, 0, stream>>>(w3, wp3);   // h1/wp2 dead after conv2
    conv_mfma<128, 256, 4, true><<<NB * 16, 256, DYN4, stream>>>(h2, wp3, b3, nullptr, partial, zp);
    fc_k<<<NB, 256, 0, stream>>>(partial, fcw, b4, (float*)d_out);
}

// Round 14
// 128.953 us; speedup vs baseline: 1.3617x; 1.3617x over previous
//
#include <hip/hip_runtime.h>
#include <stdint.h>

typedef __attribute__((ext_vector_type(8))) short short8;
typedef __attribute__((ext_vector_type(16))) float f32x16;

#define NB 32

__device__ __forceinline__ uint16_t f2bf(float f) {
    uint32_t u = __float_as_uint(f);
    u += 0x7fffu + ((u >> 16) & 1u);   // RNE
    return (uint16_t)(u >> 16);
}

// async global(16B) -> LDS, linear dest (wave-uniform base + lane*16)
__device__ __forceinline__ void gload16(const void* g, void* l) {
    __builtin_amdgcn_global_load_lds(
        (const __attribute__((address_space(1))) uint32_t*)g,
        (__attribute__((address_space(3))) uint32_t*)l, 16, 0, 0);
}

// ------- weight prep item: w[b][oc][ci][3][3] f32 -> wp[b][kk][oc][ci] bf16
template<int COUT, int CIN>
__device__ __forceinline__ void prep_w_item(int idx, const float* __restrict__ w,
                                            uint16_t* __restrict__ wp)
{
    const int ci = idx % CIN;
    const int t  = idx / CIN;
    const int oc = t % COUT;
    const int b  = t / COUT;
    const float* s = w + (size_t)idx * 9;
    #pragma unroll
    for (int k = 0; k < 9; k++)
        wp[((size_t)(b * 9 + k) * COUT + oc) * CIN + ci] = f2bf(s[k]);
}

// ------- standalone w3 prep (aliased-ws mode: must run AFTER conv2) --------
__global__ __launch_bounds__(256) void prep_w3_k(
    const float* __restrict__ w, uint16_t* __restrict__ wp)
{
    const int idx = blockIdx.x * 256 + threadIdx.x;
    if (idx < NB * 256 * 128) prep_w_item<256, 128>(idx, w, wp);
}

// ------- fused prep: zero-page + x->NHWC16 bf16 + w1 + w2 (+ w3) -----------
template<bool DO_W3>
__global__ __launch_bounds__(256) void prep_all(
    const float* __restrict__ x,  const float* __restrict__ w1,
    const float* __restrict__ w2, const float* __restrict__ w3,
    uint16_t* __restrict__ xp,  uint16_t* __restrict__ wp1,
    uint16_t* __restrict__ wp2, uint16_t* __restrict__ wp3,
    float* __restrict__ zp)
{
    int idx = blockIdx.x * 256 + threadIdx.x;
    if (idx < 4096) {                          // zero page (64 KB)
        ((float4*)zp)[idx] = make_float4(0.f, 0.f, 0.f, 0.f);
        return;
    }
    idx -= 4096;
    if (idx < 131072) {                        // x: NCHW f32 -> NHWC(ci=16) bf16
        const int xc = idx & 63, y = (idx >> 6) & 63, b = idx >> 12;
        const float* s = x + (size_t)b * 3 * 4096 + y * 64 + xc;
        const uint16_t v0 = f2bf(s[0]), v1 = f2bf(s[4096]), v2 = f2bf(s[8192]);
        short8 lo = {(short)v0, (short)v1, (short)v2, 0, 0, 0, 0, 0};
        short8 hi = {0, 0, 0, 0, 0, 0, 0, 0};
        uint16_t* d = xp + (size_t)idx * 16;
        *(short8*)d = lo;
        *(short8*)(d + 8) = hi;
        return;
    }
    idx -= 131072;
    if (idx < 18432) {                         // w1 -> wp1[b][kk][oc][ci=16]
        const int oc = idx & 63, k = (idx >> 6) % 9, b = idx / 576;
        const uint16_t v0 = f2bf(w1[((size_t)(b * 64 + oc) * 3 + 0) * 9 + k]);
        const uint16_t v1 = f2bf(w1[((size_t)(b * 64 + oc) * 3 + 1) * 9 + k]);
        const uint16_t v2 = f2bf(w1[((size_t)(b * 64 + oc) * 3 + 2) * 9 + k]);
        short8 lo = {(short)v0, (short)v1, (short)v2, 0, 0, 0, 0, 0};
        short8 hi = {0, 0, 0, 0, 0, 0, 0, 0};
        uint16_t* d = wp1 + ((size_t)(b * 9 + k) * 64 + oc) * 16;
        *(short8*)d = lo;
        *(short8*)(d + 8) = hi;
        return;
    }
    idx -= 18432;
    if (idx < 262144) {                        // w2
        prep_w_item<128, 64>(idx, w2, wp2);
        return;
    }
    if (!DO_W3) return;
    idx -= 262144;
    if (idx < 1048576) prep_w_item<256, 128>(idx, w3, wp3);
}

// ---------------- MFMA implicit-GEMM conv, 3x3 SAME, ReLU ------------------
// R14 = R7's exact loop shape (plain per-kk fragment loads + 8 MFMAs, single
// setprio pair, vmcnt(0)+__syncthreads per K-step, NO reg ping-pong, NO
// sched_barrier — the compiler schedules the 9-kk body freely; R7 measured
// best at 72.6 µs conv3) + R10's conflict-free linear LDS layout (input
// granules [rq=row*2+q][px], weights [kq=kk*2+q][oc]: every ds_read_b128 and
// gload_lds write is stride-1 in granules -> 0 bank conflicts, verified).
// Grid 1D, XCD-pinned: batch b -> XCD b%8.
template<int CIN, int COUT, int OCBLKS, bool POOL>
__global__ __launch_bounds__(256, 2) void conv_mfma(
    const uint16_t* __restrict__ in, const uint16_t* __restrict__ wp,
    const float* __restrict__ bias, uint16_t* __restrict__ out,
    float* __restrict__ partial, const float* __restrict__ zp)
{
    constexpr int IN_GA = 1344;              // 20 rq * 66 px = 1320, pad 1344
    constexpr int W_G   = 1152;              // 18 kq * 64 oc
    constexpr int IN_B  = IN_GA * 16;        // 21504 B
    constexpr int BUF_B = IN_B + W_G * 16;   // 39936 B
    constexpr int P     = OCBLKS * 8;        // blocks per batch (stripes=8)
    extern __shared__ __align__(16) char sm[];
    // layout: buf0 | buf1 | red 1024 B

    // ---- XCD-pinned decode: batch = (jj/P)*8 + (L&7)
    const int L   = blockIdx.x;
    const int xcd = L & 7;
    const int jj  = L >> 3;
    const int b   = (jj / P) * 8 + xcd;
    const int inner = jj % P;
    const int ocbase = (inner >> 3) * 64;
    const int stripe = inner & 7;
    const int y0 = stripe * 8;

    const int tid = threadIdx.x;
    const int wv = tid >> 6, l = tid & 63, q = l >> 5, ln = l & 31;
    const int NK = CIN / 16;

    // ---- staging source pointers (linear granule decode)
    const uint16_t* src_in[6];
    #pragma unroll
    for (int i = 0; i < 6; i++) {
        const int gp = i * 256 + tid;            // granule = rq*66 + px
        const int rq = gp / 66, px = gp - rq * 66;
        const int row = rq >> 1, qq = rq & 1;
        const int gy = y0 - 1 + row, gx = px - 1;
        const bool valid = (rq < 20) && ((unsigned)gy < 64u) && ((unsigned)gx < 64u);
        src_in[i] = valid ? in + ((size_t)((b * 64 + gy) * 64 + gx) * CIN + qq * 8)
                          : (const uint16_t*)zp;
    }
    const uint16_t* src_w[5];
    #pragma unroll
    for (int i = 0; i < 5; i++) {
        const int gp = i * 256 + tid;            // granule = kq*64 + oc
        const int kq = gp >> 6, oc = gp & 63;
        const int kk = kq >> 1, qq = kq & 1;
        src_w[i] = wp + ((size_t)(b * 9 + kk) * COUT + ocbase + oc) * CIN + qq * 8;
    }

    // ---- LDS read offsets (bytes): A rows t=0..3 x px-half h; +kx*16 at use
    int aoff[4][2];
    #pragma unroll
    for (int t = 0; t < 4; t++)
        #pragma unroll
        for (int h = 0; h < 2; h++)
            aoff[t][h] = ((((wv * 2 + t) * 2 + q) * 66) + h * 32 + ln) * 16;
    const int qoff = q * 1024 + ln * 16;         // B: + kk*2048; n=1 at +512

    f32x16 aA0, aA1, aB0, aB1, aC0, aC1, aD0, aD1;  // [dr][h] x [n]
    {
        const float bv0 = bias[b * COUT + ocbase + ln];
        const float bv1 = bias[b * COUT + ocbase + 32 + ln];
        #pragma unroll
        for (int r = 0; r < 16; r++) {
            aA0[r] = bv0; aB0[r] = bv0; aC0[r] = bv0; aD0[r] = bv0;
            aA1[r] = bv1; aB1[r] = bv1; aC1[r] = bv1; aD1[r] = bv1;
        }
    }

    auto stage = [&](char* base, int k) {
        const int koff = k * 16;
        #pragma unroll
        for (int i = 0; i < 6; i++) {
            const int g0 = i * 256 + wv * 64;
            if (g0 < IN_GA) gload16(src_in[i] + koff, base + g0 * 16);
        }
        #pragma unroll
        for (int i = 0; i < 5; i++) {
            const int g0 = i * 256 + wv * 64;
            if (g0 < W_G) gload16(src_w[i] + koff, base + IN_B + g0 * 16);
        }
    };

    stage(sm, 0);
    asm volatile("s_waitcnt vmcnt(0)" ::: "memory");
    __syncthreads();

    for (int k = 0; k < NK; k++) {
        const char* cb = sm + (k & 1) * BUF_B;
        if (k + 1 < NK) stage(sm + ((k + 1) & 1) * BUF_B, k + 1);
        __builtin_amdgcn_s_setprio(1);
        #pragma unroll
        for (int ky = 0; ky < 3; ky++)
            #pragma unroll
            for (int kx = 0; kx < 3; kx++) {
                const int kk = ky * 3 + kx;
                short8 fA = *(const short8*)(cb + aoff[ky][0] + kx * 16);
                short8 fB = *(const short8*)(cb + aoff[ky][1] + kx * 16);
                short8 fC = *(const short8*)(cb + aoff[ky + 1][0] + kx * 16);
                short8 fD = *(const short8*)(cb + aoff[ky + 1][1] + kx * 16);
                const char* bw = cb + IN_B + kk * 2048 + qoff;
                short8 b0 = *(const short8*)(bw);
                short8 b1 = *(const short8*)(bw + 512);
                aA0 = __builtin_amdgcn_mfma_f32_32x32x16_bf16(fA, b0, aA0, 0, 0, 0);
                aB0 = __builtin_amdgcn_mfma_f32_32x32x16_bf16(fB, b0, aB0, 0, 0, 0);
                aC0 = __builtin_amdgcn_mfma_f32_32x32x16_bf16(fC, b0, aC0, 0, 0, 0);
                aD0 = __builtin_amdgcn_mfma_f32_32x32x16_bf16(fD, b0, aD0, 0, 0, 0);
                aA1 = __builtin_amdgcn_mfma_f32_32x32x16_bf16(fA, b1, aA1, 0, 0, 0);
                aB1 = __builtin_amdgcn_mfma_f32_32x32x16_bf16(fB, b1, aB1, 0, 0, 0);
                aC1 = __builtin_amdgcn_mfma_f32_32x32x16_bf16(fC, b1, aC1, 0, 0, 0);
                aD1 = __builtin_amdgcn_mfma_f32_32x32x16_bf16(fD, b1, aD1, 0, 0, 0);
            }
        __builtin_amdgcn_s_setprio(0);
        asm volatile("s_waitcnt vmcnt(0)" ::: "memory");
        __syncthreads();
    }

    if (!POOL) {
        #pragma unroll
        for (int r = 0; r < 16; r++) {
            const int pxr = (r & 3) + 8 * (r >> 2) + 4 * q;
            const int y0w = y0 + wv * 2;
            uint16_t* dA = out + (size_t)((b * 64 + y0w) * 64 + pxr) * COUT + ocbase;
            uint16_t* dB = out + (size_t)((b * 64 + y0w) * 64 + 32 + pxr) * COUT + ocbase;
            uint16_t* dC = out + (size_t)((b * 64 + y0w + 1) * 64 + pxr) * COUT + ocbase;
            uint16_t* dD = out + (size_t)((b * 64 + y0w + 1) * 64 + 32 + pxr) * COUT + ocbase;
            dA[ln]      = f2bf(fmaxf(aA0[r], 0.f));
            dA[32 + ln] = f2bf(fmaxf(aA1[r], 0.f));
            dB[ln]      = f2bf(fmaxf(aB0[r], 0.f));
            dB[32 + ln] = f2bf(fmaxf(aB1[r], 0.f));
            dC[ln]      = f2bf(fmaxf(aC0[r], 0.f));
            dC[32 + ln] = f2bf(fmaxf(aC1[r], 0.f));
            dD[ln]      = f2bf(fmaxf(aD0[r], 0.f));
            dD[32 + ln] = f2bf(fmaxf(aD1[r], 0.f));
        }
    } else {
        float* red = (float*)(sm + 2 * BUF_B);
        float s0 = 0.f, s1 = 0.f;
        #pragma unroll
        for (int r = 0; r < 16; r++) {
            s0 += fmaxf(aA0[r], 0.f) + fmaxf(aB0[r], 0.f)
                + fmaxf(aC0[r], 0.f) + fmaxf(aD0[r], 0.f);
            s1 += fmaxf(aA1[r], 0.f) + fmaxf(aB1[r], 0.f)
                + fmaxf(aC1[r], 0.f) + fmaxf(aD1[r], 0.f);
        }
        s0 += __shfl_xor(s0, 32);
        s1 += __shfl_xor(s1, 32);
        if (q == 0) {
            red[wv * 64 + ln] = s0;
            red[wv * 64 + 32 + ln] = s1;
        }
        __syncthreads();
        if (tid < 64) {
            float t = red[tid] + red[64 + tid] + red[128 + tid] + red[192 + tid];
            partial[(size_t)(b * 256 + ocbase + tid) * 8 + stripe] = t;
        }
    }
}

// ------- pooled mean + outer product with fc weight + bias4 ----------------
__global__ void fc_k(const float* __restrict__ partial,
                     const float* __restrict__ fcw,
                     const float* __restrict__ b4, float* __restrict__ out)
{
    const int b = blockIdx.x, c = threadIdx.x;   // 32 x 256
    const float* p = partial + (size_t)(b * 256 + c) * 8;
    float s = 0.f;
    #pragma unroll
    for (int i = 0; i < 8; i++) s += p[i];
    const float pooled = s * (1.f / 4096.f);
    #pragma unroll
    for (int o = 0; o < 10; o++)
        out[(b * 256 + c) * 10 + o] = fmaf(pooled, fcw[b * 10 + o], b4[b * 10 + o]);
}

extern "C" void kernel_launch(void* const* d_in, const int* in_sizes, int n_in,
                              void* d_out, int out_size, void* d_ws, size_t ws_size,
                              hipStream_t stream)
{
    const float* x   = (const float*)d_in[0];
    const float* w1  = (const float*)d_in[1];
    const float* w2  = (const float*)d_in[2];
    const float* w3  = (const float*)d_in[3];
    const float* fcw = (const float*)d_in[4];
    const float* b1  = (const float*)d_in[5];
    const float* b2  = (const float*)d_in[6];
    const float* b3  = (const float*)d_in[7];
    const float* b4  = (const float*)d_in[8];
    char* ws = (char*)d_ws;
    // Regions (see R6 notes): xp/wp1 alias dead-until-conv2 h2 space.
    uint16_t* xp  = (uint16_t*)(ws);
    uint16_t* wp1 = (uint16_t*)(ws + 4194304);
    uint16_t* h2  = (uint16_t*)(ws);
    uint16_t* h1  = (uint16_t*)(ws + 33554432);
    uint16_t* wp2 = (uint16_t*)(ws + 50331648);
    const bool big_ws = ws_size >= 74186752u;
    uint16_t* wp3     = (uint16_t*)(ws + (big_ws ? 55050240u : 33554432u));
    float*    partial = (float*)   (ws + (big_ws ? 73924608u : 52428800u));
    float*    zp      = (float*)d_out;   // first 64 KB zeroed by prep_all

    constexpr int DYN_LDS = 2 * 39936 + 1024;   // 80896 B = 2 blocks/CU
    static bool attr_done = false;
    if (!attr_done) {   // host-side attribute set; not a stream op (capture-safe)
        hipFuncSetAttribute((const void*)&conv_mfma<16, 64, 1, false>,
                            hipFuncAttributeMaxDynamicSharedMemorySize, DYN_LDS);
        hipFuncSetAttribute((const void*)&conv_mfma<64, 128, 2, false>,
                            hipFuncAttributeMaxDynamicSharedMemorySize, DYN_LDS);
        hipFuncSetAttribute((const void*)&conv_mfma<128, 256, 4, true>,
                            hipFuncAttributeMaxDynamicSharedMemorySize, DYN_LDS);
        attr_done = true;
    }

    if (big_ws) {
        prep_all<true><<<5720, 256, 0, stream>>>(x, w1, w2, w3, xp, wp1, wp2, wp3, zp);
    } else {
        prep_all<false><<<1624, 256, 0, stream>>>(x, w1, w2, w3, xp, wp1, wp2, wp3, zp);
    }
    conv_mfma<16, 64, 1, false><<<NB * 8, 256, DYN_LDS, stream>>>(xp, wp1, b1, h1, nullptr, zp);
    conv_mfma<64, 128, 2, false><<<NB * 16, 256, DYN_LDS, stream>>>(h1, wp2, b2, h2, nullptr, zp);
    if (!big_ws)
        prep_w3_k<<<4096, 256, 0, stream>>>(w3, wp3);   // h1/wp2 dead after conv2
    conv_mfma<128, 256, 4, true><<<NB * 32, 256, DYN_LDS, stream>>>(h2, wp3, b3, nullptr, partial, zp);
    fc_k<<<NB, 256, 0, stream>>>(partial, fcw, b4, (float*)d_out);
}

// Round 15
// 128.597 us; speedup vs baseline: 1.3655x; 1.0028x over previous
//
#include <hip/hip_runtime.h>
#include <stdint.h>

typedef __attribute__((ext_vector_type(8))) short short8;
typedef __attribute__((ext_vector_type(16))) float f32x16;

#define NB 32

__device__ __forceinline__ uint16_t f2bf(float f) {
    uint32_t u = __float_as_uint(f);
    u += 0x7fffu + ((u >> 16) & 1u);   // RNE
    return (uint16_t)(u >> 16);
}

// async global(16B) -> LDS, linear dest (wave-uniform base + lane*16)
__device__ __forceinline__ void gload16(const void* g, void* l) {
    __builtin_amdgcn_global_load_lds(
        (const __attribute__((address_space(1))) uint32_t*)g,
        (__attribute__((address_space(3))) uint32_t*)l, 16, 0, 0);
}

// ------- weight prep item: w[b][oc][ci][3][3] f32 -> wp[b][kk][oc][ci] bf16
template<int COUT, int CIN>
__device__ __forceinline__ void prep_w_item(int idx, const float* __restrict__ w,
                                            uint16_t* __restrict__ wp)
{
    const int ci = idx % CIN;
    const int t  = idx / CIN;
    const int oc = t % COUT;
    const int b  = t / COUT;
    const float* s = w + (size_t)idx * 9;
    #pragma unroll
    for (int k = 0; k < 9; k++)
        wp[((size_t)(b * 9 + k) * COUT + oc) * CIN + ci] = f2bf(s[k]);
}

// ------- standalone w3 prep (aliased-ws mode: must run AFTER conv2) --------
__global__ __launch_bounds__(256) void prep_w3_k(
    const float* __restrict__ w, uint16_t* __restrict__ wp)
{
    const int idx = blockIdx.x * 256 + threadIdx.x;
    if (idx < NB * 256 * 128) prep_w_item<256, 128>(idx, w, wp);
}

// ------- fused prep: zero-page + x->NHWC16 bf16 + w1 + w2 (+ w3) -----------
template<bool DO_W3>
__global__ __launch_bounds__(256) void prep_all(
    const float* __restrict__ x,  const float* __restrict__ w1,
    const float* __restrict__ w2, const float* __restrict__ w3,
    uint16_t* __restrict__ xp,  uint16_t* __restrict__ wp1,
    uint16_t* __restrict__ wp2, uint16_t* __restrict__ wp3,
    float* __restrict__ zp)
{
    int idx = blockIdx.x * 256 + threadIdx.x;
    if (idx < 4096) {                          // zero page (64 KB)
        ((float4*)zp)[idx] = make_float4(0.f, 0.f, 0.f, 0.f);
        return;
    }
    idx -= 4096;
    if (idx < 131072) {                        // x: NCHW f32 -> NHWC(ci=16) bf16
        const int xc = idx & 63, y = (idx >> 6) & 63, b = idx >> 12;
        const float* s = x + (size_t)b * 3 * 4096 + y * 64 + xc;
        const uint16_t v0 = f2bf(s[0]), v1 = f2bf(s[4096]), v2 = f2bf(s[8192]);
        short8 lo = {(short)v0, (short)v1, (short)v2, 0, 0, 0, 0, 0};
        short8 hi = {0, 0, 0, 0, 0, 0, 0, 0};
        uint16_t* d = xp + (size_t)idx * 16;
        *(short8*)d = lo;
        *(short8*)(d + 8) = hi;
        return;
    }
    idx -= 131072;
    if (idx < 18432) {                         // w1 -> wp1[b][kk][oc][ci=16]
        const int oc = idx & 63, k = (idx >> 6) % 9, b = idx / 576;
        const uint16_t v0 = f2bf(w1[((size_t)(b * 64 + oc) * 3 + 0) * 9 + k]);
        const uint16_t v1 = f2bf(w1[((size_t)(b * 64 + oc) * 3 + 1) * 9 + k]);
        const uint16_t v2 = f2bf(w1[((size_t)(b * 64 + oc) * 3 + 2) * 9 + k]);
        short8 lo = {(short)v0, (short)v1, (short)v2, 0, 0, 0, 0, 0};
        short8 hi = {0, 0, 0, 0, 0, 0, 0, 0};
        uint16_t* d = wp1 + ((size_t)(b * 9 + k) * 64 + oc) * 16;
        *(short8*)d = lo;
        *(short8*)(d + 8) = hi;
        return;
    }
    idx -= 18432;
    if (idx < 262144) {                        // w2
        prep_w_item<128, 64>(idx, w2, wp2);
        return;
    }
    if (!DO_W3) return;
    idx -= 262144;
    if (idx < 1048576) prep_w_item<256, 128>(idx, w3, wp3);
}

// ---------------- MFMA implicit-GEMM conv, 3x3 SAME, ReLU ------------------
// R15: PHASE-SPLIT K-step (T3+T4 mechanism, m196/m201). Each K-step = 3
// ky-phases; each phase: {18 ds_reads (12 A + 6 B) | stage-issue (ph0) |
// s_barrier | lgkmcnt(0)+sched_barrier(0) | setprio(1) 24 MFMA setprio(0) |
// s_barrier}. The post-barrier MFMA cluster of phase p drains on the matrix
// pipe WHILE all waves issue phase p+1's ds_reads -> LDS/matrix overlap by
// construction (single-phase K-steps measured as the SUM of both walls,
// R7-R14). Buffer handoff: per-wave vmcnt(0) BEFORE the closing barrier of
// the last phase -> all waves' gloads landed before anyone reads the new
// buffer (vmcnt is per-wave; wait must precede a barrier).
// Layout (R10-verified conflict-free): input granules [rq=row*2+q][px],
// weights [kq=kk*2+q][oc]; all ds_reads/gload-writes stride-1 in granules.
// Grid 1D, XCD-pinned: batch b -> XCD b%8.
template<int CIN, int COUT, int OCBLKS, bool POOL>
__global__ __launch_bounds__(256, 2) void conv_mfma(
    const uint16_t* __restrict__ in, const uint16_t* __restrict__ wp,
    const float* __restrict__ bias, uint16_t* __restrict__ out,
    float* __restrict__ partial, const float* __restrict__ zp)
{
    constexpr int IN_GA = 1344;              // 20 rq * 66 px = 1320, pad 1344
    constexpr int W_G   = 1152;              // 18 kq * 64 oc
    constexpr int IN_B  = IN_GA * 16;        // 21504 B
    constexpr int BUF_B = IN_B + W_G * 16;   // 39936 B
    constexpr int P     = OCBLKS * 8;        // blocks per batch (stripes=8)
    extern __shared__ __align__(16) char sm[];
    // layout: buf0 | buf1 | red 1024 B

    // ---- XCD-pinned decode: batch = (jj/P)*8 + (L&7)
    const int L   = blockIdx.x;
    const int xcd = L & 7;
    const int jj  = L >> 3;
    const int b   = (jj / P) * 8 + xcd;
    const int inner = jj % P;
    const int ocbase = (inner >> 3) * 64;
    const int stripe = inner & 7;
    const int y0 = stripe * 8;

    const int tid = threadIdx.x;
    const int wv = tid >> 6, l = tid & 63, q = l >> 5, ln = l & 31;
    const int NK = CIN / 16;

    // ---- staging source pointers (linear granule decode)
    const uint16_t* src_in[6];
    #pragma unroll
    for (int i = 0; i < 6; i++) {
        const int gp = i * 256 + tid;            // granule = rq*66 + px
        const int rq = gp / 66, px = gp - rq * 66;
        const int row = rq >> 1, qq = rq & 1;
        const int gy = y0 - 1 + row, gx = px - 1;
        const bool valid = (rq < 20) && ((unsigned)gy < 64u) && ((unsigned)gx < 64u);
        src_in[i] = valid ? in + ((size_t)((b * 64 + gy) * 64 + gx) * CIN + qq * 8)
                          : (const uint16_t*)zp;
    }
    const uint16_t* src_w[5];
    #pragma unroll
    for (int i = 0; i < 5; i++) {
        const int gp = i * 256 + tid;            // granule = kq*64 + oc
        const int kq = gp >> 6, oc = gp & 63;
        const int kk = kq >> 1, qq = kq & 1;
        src_w[i] = wp + ((size_t)(b * 9 + kk) * COUT + ocbase + oc) * CIN + qq * 8;
    }

    // ---- LDS read offsets (bytes): A rows t=0..3 x px-half h; +kx*16 at use
    int aoff[4][2];
    #pragma unroll
    for (int t = 0; t < 4; t++)
        #pragma unroll
        for (int h = 0; h < 2; h++)
            aoff[t][h] = ((((wv * 2 + t) * 2 + q) * 66) + h * 32 + ln) * 16;
    const int qoff = q * 1024 + ln * 16;         // B: + kk*2048; n=1 at +512

    f32x16 aA0, aA1, aB0, aB1, aC0, aC1, aD0, aD1;  // [dr][h] x [n]
    {
        const float bv0 = bias[b * COUT + ocbase + ln];
        const float bv1 = bias[b * COUT + ocbase + 32 + ln];
        #pragma unroll
        for (int r = 0; r < 16; r++) {
            aA0[r] = bv0; aB0[r] = bv0; aC0[r] = bv0; aD0[r] = bv0;
            aA1[r] = bv1; aB1[r] = bv1; aC1[r] = bv1; aD1[r] = bv1;
        }
    }

    auto stage = [&](char* base, int k) {
        const int koff = k * 16;
        #pragma unroll
        for (int i = 0; i < 6; i++) {
            const int g0 = i * 256 + wv * 64;
            if (g0 < IN_GA) gload16(src_in[i] + koff, base + g0 * 16);
        }
        #pragma unroll
        for (int i = 0; i < 5; i++) {
            const int g0 = i * 256 + wv * 64;
            if (g0 < W_G) gload16(src_w[i] + koff, base + IN_B + g0 * 16);
        }
    };

    stage(sm, 0);
    asm volatile("s_waitcnt vmcnt(0)" ::: "memory");
    __syncthreads();

    for (int k = 0; k < NK; k++) {
        const char* cb = sm + (k & 1) * BUF_B;
        #pragma unroll
        for (int ph = 0; ph < 3; ph++) {         // ph = ky
            // ---- 18 ds_reads for this ky-phase (issue; drain at lgkmcnt)
            short8 fA[2][2][3];                  // [dr][h][kx]
            short8 fB[2][3];                     // [n][kx]
            #pragma unroll
            for (int dr = 0; dr < 2; dr++)
                #pragma unroll
                for (int h = 0; h < 2; h++)
                    #pragma unroll
                    for (int kx = 0; kx < 3; kx++)
                        fA[dr][h][kx] = *(const short8*)(cb + aoff[ph + dr][h] + kx * 16);
            #pragma unroll
            for (int kx = 0; kx < 3; kx++) {
                const char* bw = cb + IN_B + (ph * 3 + kx) * 2048 + qoff;
                fB[0][kx] = *(const short8*)(bw);
                fB[1][kx] = *(const short8*)(bw + 512);
            }
            if (ph == 0 && k + 1 < NK)           // prefetch next K-step
                stage(sm + ((k + 1) & 1) * BUF_B, k + 1);
            __builtin_amdgcn_s_barrier();        // role flip: all waves ready
            asm volatile("s_waitcnt lgkmcnt(0)" ::: "memory");
            __builtin_amdgcn_sched_barrier(0);   // rule #18: pin MFMAs below
            __builtin_amdgcn_s_setprio(1);
            #pragma unroll
            for (int kx = 0; kx < 3; kx++) {
                aA0 = __builtin_amdgcn_mfma_f32_32x32x16_bf16(fA[0][0][kx], fB[0][kx], aA0, 0, 0, 0);
                aB0 = __builtin_amdgcn_mfma_f32_32x32x16_bf16(fA[0][1][kx], fB[0][kx], aB0, 0, 0, 0);
                aC0 = __builtin_amdgcn_mfma_f32_32x32x16_bf16(fA[1][0][kx], fB[0][kx], aC0, 0, 0, 0);
                aD0 = __builtin_amdgcn_mfma_f32_32x32x16_bf16(fA[1][1][kx], fB[0][kx], aD0, 0, 0, 0);
                aA1 = __builtin_amdgcn_mfma_f32_32x32x16_bf16(fA[0][0][kx], fB[1][kx], aA1, 0, 0, 0);
                aB1 = __builtin_amdgcn_mfma_f32_32x32x16_bf16(fA[0][1][kx], fB[1][kx], aB1, 0, 0, 0);
                aC1 = __builtin_amdgcn_mfma_f32_32x32x16_bf16(fA[1][0][kx], fB[1][kx], aC1, 0, 0, 0);
                aD1 = __builtin_amdgcn_mfma_f32_32x32x16_bf16(fA[1][1][kx], fB[1][kx], aD1, 0, 0, 0);
            }
            __builtin_amdgcn_s_setprio(0);
            if (ph == 2)                          // buffer handoff: per-wave
                asm volatile("s_waitcnt vmcnt(0)" ::: "memory");
            __builtin_amdgcn_s_barrier();        // cluster drains under next reads
        }
    }

    if (!POOL) {
        #pragma unroll
        for (int r = 0; r < 16; r++) {
            const int pxr = (r & 3) + 8 * (r >> 2) + 4 * q;
            const int y0w = y0 + wv * 2;
            uint16_t* dA = out + (size_t)((b * 64 + y0w) * 64 + pxr) * COUT + ocbase;
            uint16_t* dB = out + (size_t)((b * 64 + y0w) * 64 + 32 + pxr) * COUT + ocbase;
            uint16_t* dC = out + (size_t)((b * 64 + y0w + 1) * 64 + pxr) * COUT + ocbase;
            uint16_t* dD = out + (size_t)((b * 64 + y0w + 1) * 64 + 32 + pxr) * COUT + ocbase;
            dA[ln]      = f2bf(fmaxf(aA0[r], 0.f));
            dA[32 + ln] = f2bf(fmaxf(aA1[r], 0.f));
            dB[ln]      = f2bf(fmaxf(aB0[r], 0.f));
            dB[32 + ln] = f2bf(fmaxf(aB1[r], 0.f));
            dC[ln]      = f2bf(fmaxf(aC0[r], 0.f));
            dC[32 + ln] = f2bf(fmaxf(aC1[r], 0.f));
            dD[ln]      = f2bf(fmaxf(aD0[r], 0.f));
            dD[32 + ln] = f2bf(fmaxf(aD1[r], 0.f));
        }
    } else {
        float* red = (float*)(sm + 2 * BUF_B);
        float s0 = 0.f, s1 = 0.f;
        #pragma unroll
        for (int r = 0; r < 16; r++) {
            s0 += fmaxf(aA0[r], 0.f) + fmaxf(aB0[r], 0.f)
                + fmaxf(aC0[r], 0.f) + fmaxf(aD0[r], 0.f);
            s1 += fmaxf(aA1[r], 0.f) + fmaxf(aB1[r], 0.f)
                + fmaxf(aC1[r], 0.f) + fmaxf(aD1[r], 0.f);
        }
        s0 += __shfl_xor(s0, 32);
        s1 += __shfl_xor(s1, 32);
        if (q == 0) {
            red[wv * 64 + ln] = s0;
            red[wv * 64 + 32 + ln] = s1;
        }
        __syncthreads();
        if (tid < 64) {
            float t = red[tid] + red[64 + tid] + red[128 + tid] + red[192 + tid];
            partial[(size_t)(b * 256 + ocbase + tid) * 8 + stripe] = t;
        }
    }
}

// ------- pooled mean + outer product with fc weight + bias4 ----------------
__global__ void fc_k(const float* __restrict__ partial,
                     const float* __restrict__ fcw,
                     const float* __restrict__ b4, float* __restrict__ out)
{
    const int b = blockIdx.x, c = threadIdx.x;   // 32 x 256
    const float* p = partial + (size_t)(b * 256 + c) * 8;
    float s = 0.f;
    #pragma unroll
    for (int i = 0; i < 8; i++) s += p[i];
    const float pooled = s * (1.f / 4096.f);
    #pragma unroll
    for (int o = 0; o < 10; o++)
        out[(b * 256 + c) * 10 + o] = fmaf(pooled, fcw[b * 10 + o], b4[b * 10 + o]);
}

extern "C" void kernel_launch(void* const* d_in, const int* in_sizes, int n_in,
                              void* d_out, int out_size, void* d_ws, size_t ws_size,
                              hipStream_t stream)
{
    const float* x   = (const float*)d_in[0];
    const float* w1  = (const float*)d_in[1];
    const float* w2  = (const float*)d_in[2];
    const float* w3  = (const float*)d_in[3];
    const float* fcw = (const float*)d_in[4];
    const float* b1  = (const float*)d_in[5];
    const float* b2  = (const float*)d_in[6];
    const float* b3  = (const float*)d_in[7];
    const float* b4  = (const float*)d_in[8];
    char* ws = (char*)d_ws;
    // Regions (see R6 notes): xp/wp1 alias dead-until-conv2 h2 space.
    uint16_t* xp  = (uint16_t*)(ws);
    uint16_t* wp1 = (uint16_t*)(ws + 4194304);
    uint16_t* h2  = (uint16_t*)(ws);
    uint16_t* h1  = (uint16_t*)(ws + 33554432);
    uint16_t* wp2 = (uint16_t*)(ws + 50331648);
    const bool big_ws = ws_size >= 74186752u;
    uint16_t* wp3     = (uint16_t*)(ws + (big_ws ? 55050240u : 33554432u));
    float*    partial = (float*)   (ws + (big_ws ? 73924608u : 52428800u));
    float*    zp      = (float*)d_out;   // first 64 KB zeroed by prep_all

    constexpr int DYN_LDS = 2 * 39936 + 1024;   // 80896 B = 2 blocks/CU
    static bool attr_done = false;
    if (!attr_done) {   // host-side attribute set; not a stream op (capture-safe)
        hipFuncSetAttribute((const void*)&conv_mfma<16, 64, 1, false>,
                            hipFuncAttributeMaxDynamicSharedMemorySize, DYN_LDS);
        hipFuncSetAttribute((const void*)&conv_mfma<64, 128, 2, false>,
                            hipFuncAttributeMaxDynamicSharedMemorySize, DYN_LDS);
        hipFuncSetAttribute((const void*)&conv_mfma<128, 256, 4, true>,
                            hipFuncAttributeMaxDynamicSharedMemorySize, DYN_LDS);
        attr_done = true;
    }

    if (big_ws) {
        prep_all<true><<<5720, 256, 0, stream>>>(x, w1, w2, w3, xp, wp1, wp2, wp3, zp);
    } else {
        prep_all<false><<<1624, 256, 0, stream>>>(x, w1, w2, w3, xp, wp1, wp2, wp3, zp);
    }
    conv_mfma<16, 64, 1, false><<<NB * 8, 256, DYN_LDS, stream>>>(xp, wp1, b1, h1, nullptr, zp);
    conv_mfma<64, 128, 2, false><<<NB * 16, 256, DYN_LDS, stream>>>(h1, wp2, b2, h2, nullptr, zp);
    if (!big_ws)
        prep_w3_k<<<4096, 256, 0, stream>>>(w3, wp3);   // h1/wp2 dead after conv2
    conv_mfma<128, 256, 4, true><<<NB * 32, 256, DYN_LDS, stream>>>(h2, wp3, b3, nullptr, partial, zp);
    fc_k<<<NB, 256, 0, stream>>>(partial, fcw, b4, (float*)d_out);
}